// Round 17
// baseline (109.765 us; speedup 1.0000x reference)
//
#include <hip/hip_runtime.h>

typedef unsigned short u16;
typedef unsigned int u32;
typedef unsigned long long u64;
typedef __attribute__((ext_vector_type(8))) short bf16x8;
typedef __attribute__((ext_vector_type(8))) _Float16 f16x8;
typedef __attribute__((ext_vector_type(4))) float f32x4;
typedef __attribute__((ext_vector_type(4))) u32 u32x4;

#define GLOAD16(gp, lp) __builtin_amdgcn_global_load_lds( \
  (const __attribute__((address_space(1))) unsigned int*)(gp), \
  (__attribute__((address_space(3))) unsigned int*)(lp), 16, 0, 0)

__device__ __forceinline__ u16 f2bf(float f) {
  unsigned int u = __builtin_bit_cast(unsigned int, f);
  u += 0x7fffu + ((u >> 16) & 1u);   // RNE
  return (u16)(u >> 16);
}

// packed f32x2 -> bf16x2 (bit-op RNE; compiler schedules freely)
__device__ __forceinline__ u32 pk2(float a, float b) {
  return (u32)f2bf(a) | ((u32)f2bf(b) << 16);
}

// packed f32x2 -> f16x2 via hardware v_cvt_pkrtz_f16_f32 (single op)
__device__ __forceinline__ u32 pkh(float a, float b) {
  return __builtin_bit_cast(u32, __builtin_amdgcn_cvt_pkrtz(a, b));
}

// Counted-prefetch barrier: wait for the PREVIOUS iteration's staging (its
// latency was hidden under a full iteration of compute), then raw barrier.
// sched_barrier keeps the compiler from hoisting LDS reads above it.
__device__ __forceinline__ void wait_barrier() {
  asm volatile("s_waitcnt vmcnt(0)" ::: "memory");
  __builtin_amdgcn_s_barrier();
  __builtin_amdgcn_sched_barrier(0);
}

// ---------------------------------------------------------------- converts
// One launch for x + all 4 weights: grid 8192 blocks x 1024 elems.
__global__ __launch_bounds__(256) void cvt_all(
    const float* __restrict__ x,
    const float* __restrict__ w0, const float* __restrict__ w1,
    const float* __restrict__ w2, const float* __restrict__ w3,
    u16* __restrict__ ox, u16* __restrict__ o0, u16* __restrict__ o1,
    u16* __restrict__ o2, u16* __restrict__ o3) {
  int bid = blockIdx.x;
  const float* in; u16* out; size_t off;
  if (bid < 4096) {
    in = x; out = ox; off = (size_t)bid << 10;
  } else {
    int r = bid - 4096, z = r >> 10;
    in  = (z == 0) ? w0 : (z == 1) ? w1 : (z == 2) ? w2 : w3;
    out = (z == 0) ? o0 : (z == 1) ? o1 : (z == 2) ? o2 : o3;
    off = (size_t)(r & 1023) << 10;
  }
  size_t i = off + (size_t)threadIdx.x * 4;
  float4 f = *reinterpret_cast<const float4*>(in + i);
  u64 v = (u64)pk2(f.x, f.y) | ((u64)pk2(f.z, f.w) << 32);
  *reinterpret_cast<u64*>(out + i) = v;
}

// ---------------------------------------------------------------- GEMM (B^T)
// C[m,n] = sum_k A[m,k] * Bw[n,k]; Bw:[1024,1024] bf16.
// Tile MT x NT, BK=32, 4 waves (2x2). Counted-prefetch schedule.
template<int MODE, int MT, int NT>  // MODE 0: bf16 [B,H,T,D] (scaled); 1: fp32 [M,1024]
__device__ __forceinline__ void gemm_bt_body(
    const u16* __restrict__ A, const u16* __restrict__ Bw, void* __restrict__ Cout,
    int m0, int n0, float scale) {
  const int K = 1024;
  __shared__ __align__(16) u16 As[2][MT * 32];
  __shared__ __align__(16) u16 Bs[2][NT * 32];
  const int tid = threadIdx.x;
  const int lane = tid & 63, wid = tid >> 6;
  const int wr = wid >> 1, wc = wid & 1;
  const int g = lane >> 4, c = lane & 15;
  f32x4 acc[MT / 32][NT / 32] = {};

  auto stage = [&](int buf, int k0) {
#pragma unroll
    for (int i = 0; i < MT / 64; ++i) {
      int idx = tid + i * 256;
      int row = idx >> 2, slot = idx & 3;
      int ss = slot ^ (row & 3);
      GLOAD16(A + (size_t)(m0 + row) * K + k0 + ss * 8, &As[buf][idx * 8]);
    }
#pragma unroll
    for (int i = 0; i < NT / 64; ++i) {
      int idx = tid + i * 256;
      int row = idx >> 2, slot = idx & 3;
      int ss = slot ^ (row & 3);
      GLOAD16(Bw + (size_t)(n0 + row) * K + k0 + ss * 8, &Bs[buf][idx * 8]);
    }
  };

  stage(0, 0);
  int buf = 0;
#pragma unroll 1
  for (int kt = 0; kt < 32; ++kt) {
    wait_barrier();
    if (kt + 1 < 32) stage(buf ^ 1, (kt + 1) * 32);
    bf16x8 af[MT / 32], bfr[NT / 32];
#pragma unroll
    for (int mi = 0; mi < MT / 32; ++mi) {
      int row = wr * (MT / 2) + mi * 16 + c;
      int slot = g ^ (row & 3);
      af[mi] = *(const bf16x8*)&As[buf][row * 32 + slot * 8];
    }
#pragma unroll
    for (int ni = 0; ni < NT / 32; ++ni) {
      int row = wc * (NT / 2) + ni * 16 + c;
      int slot = g ^ (row & 3);
      bfr[ni] = *(const bf16x8*)&Bs[buf][row * 32 + slot * 8];
    }
    __builtin_amdgcn_s_setprio(1);
#pragma unroll
    for (int mi = 0; mi < MT / 32; ++mi)
#pragma unroll
      for (int ni = 0; ni < NT / 32; ++ni)
        acc[mi][ni] = __builtin_amdgcn_mfma_f32_16x16x32_bf16(af[mi], bfr[ni], acc[mi][ni], 0, 0, 0);
    __builtin_amdgcn_s_setprio(0);
    buf ^= 1;
  }

#pragma unroll
  for (int mi = 0; mi < MT / 32; ++mi)
#pragma unroll
    for (int ni = 0; ni < NT / 32; ++ni)
#pragma unroll
      for (int i = 0; i < 4; ++i) {
        int m = m0 + wr * (MT / 2) + mi * 16 + g * 4 + i;
        int n = n0 + wc * (NT / 2) + ni * 16 + c;
        float v = acc[mi][ni][i];
        if (MODE == 0) {
          int b = m >> 11, t = m & 2047, h = n >> 6, d = n & 63;
          ((u16*)Cout)[(((size_t)b * 16 + h) * 2048 + t) * 64 + d] = f2bf(v * scale);
        } else {
          ((float*)Cout)[(size_t)m * 1024 + n] = v;
        }
      }
}

// Q is pre-scaled by (1/sqrt(D)) * log2(e) so attn scores are in log2 domain.
#define QSCALE 0.1803368801111204f

__global__ __launch_bounds__(256, 3) void proj_qkv(
    const u16* __restrict__ xb, const u16* __restrict__ wq, const u16* __restrict__ wk,
    const u16* __restrict__ wv, u16* __restrict__ q, u16* __restrict__ k, u16* __restrict__ v) {
  int z = blockIdx.z;
  const u16* W = (z == 0) ? wq : (z == 1) ? wk : wv;
  u16* O = (z == 0) ? q : (z == 1) ? k : v;
  float scale = (z == 0) ? QSCALE : 1.0f;
  gemm_bt_body<0, 128, 128>(xb, W, O, blockIdx.y * 128, blockIdx.x * 128, scale);
}

// 64x64 tiles: grid (16, 64) = 1024 blocks -> 4 blocks/CU.
__global__ __launch_bounds__(256, 4) void gemm_out(
    const u16* __restrict__ y, const u16* __restrict__ wp, float* __restrict__ out) {
  gemm_bt_body<1, 64, 64>(y, wp, out, blockIdx.y * 64, blockIdx.x * 64, 1.0f);
}

// ---------------------------------------------------------------- V transpose
// v [B,H,T,64] bf16 -> vt [B,H,64,T] FP16, with per-64-tile key permutation:
// storage slot j holds real key real(j) = (2*((j>>2)&1) + (j>>5))*16
// + ((j>>3)&3)*4 + (j&3). This matches the in-register P fragment produced by
// the swapped QK^T in attn, so PV contracts correctly.
__global__ __launch_bounds__(256) void transpose_v_kernel(
    const u16* __restrict__ v, u16* __restrict__ vt) {
  __shared__ u16 tile[64][65];
  int bh = blockIdx.y, t0 = blockIdx.x * 64;
  const u16* src = v + ((size_t)bh * 2048 + t0) * 64;
  u16* dst = vt + (size_t)bh * 64 * 2048 + t0;
  int tid = threadIdx.x;
#pragma unroll
  for (int i = 0; i < 16; ++i) {
    int idx = tid + i * 256;
    tile[idx >> 6][idx & 63] = src[idx];
  }
  __syncthreads();
#pragma unroll
  for (int i = 0; i < 16; ++i) {
    int idx = tid + i * 256;
    int d = idx >> 6, j = idx & 63;
    int t = (((((j >> 2) & 1) << 1) | (j >> 5)) << 4) | (((j >> 3) & 3) << 2) | (j & 3);
    float f = __builtin_bit_cast(float, (u32)tile[t][d] << 16);
    _Float16 hh = (_Float16)f;
    dst[(size_t)d * 2048 + j] = __builtin_bit_cast(u16, hh);
  }
}

// ---------------------------------------------------------------- flash attention
// SPLIT-K flash: grid (32 bh, 48). yy<32: qt=16+(yy>>1), part=yy&1 — the two
// parts each cover half the key tiles and write RAW fp32 (O,l) partials
// (fixed-base softmax => partials are EXACTLY additive: O=O0+O1, l=l0+l1,
// no max bookkeeping). yy>=32: qt=47-yy (<16), single block, writes y direct.
// Max block length drops 32 -> 17 k-iters; 1536 blocks at 4/CU backfill
// => CU slot utilization ~97% vs ~52%. Part-0 never touches the diagonal
// (h1 <= 16 <= qt) so it skips masking. All inner machinery = round 16:
// swapped QK^T, in-register fp16 P, permuted V, MFMA row-sums,
// counted-prefetch barrier, 32KB LDS, 4 blocks/CU.
__global__ __launch_bounds__(256, 4) void attn_kernel(
    const u16* __restrict__ q, const u16* __restrict__ kg,
    const u16* __restrict__ vt, u16* __restrict__ y,
    float* __restrict__ Os, float* __restrict__ Ls) {
  const int T = 2048;
  __shared__ __align__(16) u16 Ks[2][64 * 64];   // [key][d] bf16
  __shared__ __align__(16) u16 Vs[2][64 * 64];   // [d][key-slot] fp16 (perm'd)
  const int tid = threadIdx.x, lane = tid & 63, w = tid >> 6;
  const int g = lane >> 4, c = lane & 15;
  const int bh = blockIdx.x;
  const int yy = blockIdx.y;
  const bool partial = (yy < 32);
  int qt, k0t, k1t, part = 0;
  if (partial) {
    qt = 16 + (yy >> 1);
    part = yy & 1;
    int nt = qt + 1, h1 = nt >> 1;
    k0t = part ? h1 : 0;
    k1t = part ? nt : h1;
  } else {
    qt = 47 - yy;
    k0t = 0;
    k1t = qt + 1;
  }
  const u16* Q = q + (size_t)bh * T * 64;
  const u16* K = kg + (size_t)bh * T * 64;
  const u16* V = vt + (size_t)bh * 64 * T;
  const int b = bh >> 4, h = bh & 15;
  const int qrow0 = qt * 64 + w * 16;

  f16x8 ones;
#pragma unroll
  for (int j = 0; j < 8; ++j) ones[j] = (_Float16)1.0f;

  auto stage = [&](int bb, int j0) {
#pragma unroll
    for (int i = 0; i < 2; ++i) {
      int idx = tid + i * 256;
      int row = idx >> 3, slot = idx & 7;
      int ss = slot ^ (row & 7);
      GLOAD16(K + (size_t)(j0 + row) * 64 + ss * 8, &Ks[bb][idx * 8]);
      GLOAD16(V + (size_t)row * T + j0 + ss * 8, &Vs[bb][idx * 8]);
    }
  };

  bf16x8 qf[2];
#pragma unroll
  for (int kk = 0; kk < 2; ++kk)
    qf[kk] = *(const bf16x8*)&Q[(size_t)(qrow0 + c) * 64 + kk * 32 + g * 8];

  f32x4 o[4] = {};
  f32x4 ol = {};   // row-sums (every column identical)

  stage(0, k0t * 64);
  int buf = 0;
#pragma unroll 1
  for (int kt = k0t; kt < k1t; ++kt) {
    const int j0 = kt * 64;
    wait_barrier();
    if (kt + 1 < k1t) stage(buf ^ 1, j0 + 64);

    // S^T = K Q^T: s[ni][i] = S[q-row qrow0+c][key j0 + ni*16 + g*4 + i]
    bf16x8 kb[4][2];
#pragma unroll
    for (int ni = 0; ni < 4; ++ni)
#pragma unroll
      for (int kk = 0; kk < 2; ++kk) {
        int kr = ni * 16 + c;
        int slot = (kk * 4 + g) ^ (kr & 7);
        kb[ni][kk] = *(const bf16x8*)&Ks[buf][kr * 64 + slot * 8];
      }
    f32x4 s[4];
    __builtin_amdgcn_s_setprio(1);
#pragma unroll
    for (int ni = 0; ni < 4; ++ni) {
      f32x4 a = {0.f, 0.f, 0.f, 0.f};
      a = __builtin_amdgcn_mfma_f32_16x16x32_bf16(kb[ni][0], qf[0], a, 0, 0, 0);
      a = __builtin_amdgcn_mfma_f32_16x16x32_bf16(kb[ni][1], qf[1], a, 0, 0, 0);
      s[ni] = a;
    }
    __builtin_amdgcn_s_setprio(0);

    // p = exp2(s); causal mask -> -inf -> 0 (only diag tile masks)
    const bool dumask = (kt == qt);
#pragma unroll
    for (int ni = 0; ni < 4; ++ni)
#pragma unroll
      for (int i = 0; i < 4; ++i) {
        float val = s[ni][i];
        if (dumask) {
          int key = j0 + ni * 16 + g * 4 + i;
          if (key > qrow0 + c) val = -3.0e38f;
        }
        s[ni][i] = __builtin_amdgcn_exp2f(val);
      }

    // In-register P fragment (fp16): storage slot b*32+g*8+q*4+i holds real
    // key (2q+b)*16+g*4+i = s[2q+b][i]. Matches V's storage permutation.
    u32x4 pa0 = { pkh(s[0][0], s[0][1]), pkh(s[0][2], s[0][3]),
                  pkh(s[2][0], s[2][1]), pkh(s[2][2], s[2][3]) };
    u32x4 pa1 = { pkh(s[1][0], s[1][1]), pkh(s[1][2], s[1][3]),
                  pkh(s[3][0], s[3][1]), pkh(s[3][2], s[3][3]) };
    f16x8 pa[2];
    pa[0] = __builtin_bit_cast(f16x8, pa0);
    pa[1] = __builtin_bit_cast(f16x8, pa1);

    // O += P @ V; l += P @ 1 (fp16 inputs, fp32 accum)
    f16x8 vb[4][2];
#pragma unroll
    for (int di = 0; di < 4; ++di)
#pragma unroll
      for (int kk = 0; kk < 2; ++kk) {
        int d = di * 16 + c;
        int slot = (kk * 4 + g) ^ (d & 7);
        vb[di][kk] = *(const f16x8*)&Vs[buf][d * 64 + slot * 8];
      }
    __builtin_amdgcn_s_setprio(1);
    ol = __builtin_amdgcn_mfma_f32_16x16x32_f16(pa[0], ones, ol, 0, 0, 0);
    ol = __builtin_amdgcn_mfma_f32_16x16x32_f16(pa[1], ones, ol, 0, 0, 0);
#pragma unroll
    for (int di = 0; di < 4; ++di) {
      o[di] = __builtin_amdgcn_mfma_f32_16x16x32_f16(pa[0], vb[di][0], o[di], 0, 0, 0);
      o[di] = __builtin_amdgcn_mfma_f32_16x16x32_f16(pa[1], vb[di][1], o[di], 0, 0, 0);
    }
    __builtin_amdgcn_s_setprio(0);
    buf ^= 1;
  }

  if (!partial) {
    // epilogue: y[b, t, h*64 + d] = o / l
#pragma unroll
    for (int i = 0; i < 4; ++i) {
      float inv = 1.f / ol[i];
      int t = qrow0 + g * 4 + i;
#pragma unroll
      for (int di = 0; di < 4; ++di) {
        int col = h * 64 + di * 16 + c;
        y[((size_t)b * 2048 + t) * 1024 + col] = f2bf(o[di][i] * inv);
      }
    }
  } else {
    // raw partial write: O (fp32 64x64) + l (fp32 64) for this (tile, part)
    int tile = (bh << 4) + (qt - 16);
    float* Op = Os + ((size_t)(tile * 2 + part) << 12);
#pragma unroll
    for (int i = 0; i < 4; ++i) {
      int row = w * 16 + g * 4 + i;
#pragma unroll
      for (int di = 0; di < 4; ++di)
        Op[row * 64 + di * 16 + c] = o[di][i];
    }
    if (c == 0) {
      float* Lp = Ls + ((tile * 2 + part) << 6);
#pragma unroll
      for (int i = 0; i < 4; ++i)
        Lp[w * 16 + g * 4 + i] = ol[i];
    }
  }
}

// ---------------------------------------------------------------- combine
// y[tile rows] = (O0 + O1) / (l0 + l1) for the 512 split q-tiles (qt >= 16).
__global__ __launch_bounds__(256) void attn_combine(
    const float* __restrict__ Os, const float* __restrict__ Ls,
    u16* __restrict__ y) {
  int tile = blockIdx.x, t = threadIdx.x;
  int bh = tile >> 4, qt = 16 + (tile & 15);
  int b = bh >> 4, h = bh & 15;
  const float* O0 = Os + ((size_t)tile * 2 << 12);
  const float* O1 = O0 + 4096;
  const float* L0 = Ls + ((size_t)tile * 2 << 6);
  const float* L1 = L0 + 64;
#pragma unroll
  for (int j = 0; j < 16; ++j) {
    int e = j * 256 + t;
    int row = e >> 6, d = e & 63;
    float l = L0[row] + L1[row];
    float v = (O0[e] + O1[e]) / l;
    y[((size_t)b * 2048 + qt * 64 + row) * 1024 + h * 64 + d] = f2bf(v);
  }
}

// ---------------------------------------------------------------- launch
extern "C" void kernel_launch(void* const* d_in, const int* in_sizes, int n_in,
                              void* d_out, int out_size, void* d_ws, size_t ws_size,
                              hipStream_t stream) {
  // setup_inputs order: x, Wk, Wq, Wv, Wp
  const float* x  = (const float*)d_in[0];
  const float* Wk = (const float*)d_in[1];
  const float* Wq = (const float*)d_in[2];
  const float* Wv = (const float*)d_in[3];
  const float* Wp = (const float*)d_in[4];
  float* out = (float*)d_out;

  char* ws = (char*)d_ws;
  const size_t SZ_X = (size_t)4096 * 1024 * 2;  // 8 MiB (x_bf16 / q / k / v each)
  const size_t SZ_W = (size_t)1024 * 1024 * 2;  // 2 MiB per weight
  u16* xb  = (u16*)(ws);                  // x bf16; reused as vt (fp16) after proj
  u16* qb  = (u16*)(ws + SZ_X);
  u16* kb  = (u16*)(ws + 2 * SZ_X);
  u16* vb  = (u16*)(ws + 3 * SZ_X);       // v [B,H,T,D]; reused as y after transpose
  u16* wqb = (u16*)(ws + 4 * SZ_X);
  u16* wkb = (u16*)(ws + 4 * SZ_X + SZ_W);
  u16* wvb = (u16*)(ws + 4 * SZ_X + 2 * SZ_W);
  u16* wpb = (u16*)(ws + 4 * SZ_X + 3 * SZ_W);
  // total workspace: 40 MiB

  cvt_all<<<8192, 256, 0, stream>>>(x, Wq, Wk, Wv, Wp, xb, wqb, wkb, wvb, wpb);

  proj_qkv<<<dim3(8, 32, 3), 256, 0, stream>>>(xb, wqb, wkb, wvb, qb, kb, vb);

  u16* vtb = xb;  // x_bf16 is dead after projections
  transpose_v_kernel<<<dim3(32, 32), 256, 0, stream>>>(vb, vtb);

  // Split-K attention scratch: partial O lives in d_out (16.78 MB, exactly
  // out_size*4 bytes; fully overwritten by gemm_out afterwards), partial l
  // in the dead wqb region (weights consumed by proj).
  float* Os = out;
  float* Ls = (float*)wqb;

  u16* yb = vb;   // v [B,H,T,D] is dead after transpose
  attn_kernel<<<dim3(32, 48), 256, 0, stream>>>(qb, kb, vtb, yb, Os, Ls);
  attn_combine<<<512, 256, 0, stream>>>(Os, Ls, yb);

  gemm_out<<<dim3(16, 64), 256, 0, stream>>>(yb, wpb, out);
}

// Round 18
// 108.641 us; speedup vs baseline: 1.0103x; 1.0103x over previous
//
#include <hip/hip_runtime.h>

typedef unsigned short u16;
typedef unsigned int u32;
typedef unsigned long long u64;
typedef __attribute__((ext_vector_type(8))) short bf16x8;
typedef __attribute__((ext_vector_type(8))) _Float16 f16x8;
typedef __attribute__((ext_vector_type(4))) float f32x4;
typedef __attribute__((ext_vector_type(4))) u32 u32x4;

#define GLOAD16(gp, lp) __builtin_amdgcn_global_load_lds( \
  (const __attribute__((address_space(1))) unsigned int*)(gp), \
  (__attribute__((address_space(3))) unsigned int*)(lp), 16, 0, 0)

__device__ __forceinline__ u16 f2bf(float f) {
  unsigned int u = __builtin_bit_cast(unsigned int, f);
  u += 0x7fffu + ((u >> 16) & 1u);   // RNE
  return (u16)(u >> 16);
}

// packed f32x2 -> bf16x2 (bit-op RNE; compiler schedules freely)
__device__ __forceinline__ u32 pk2(float a, float b) {
  return (u32)f2bf(a) | ((u32)f2bf(b) << 16);
}

// packed f32x2 -> f16x2 via hardware v_cvt_pkrtz_f16_f32 (single op)
__device__ __forceinline__ u32 pkh(float a, float b) {
  return __builtin_bit_cast(u32, __builtin_amdgcn_cvt_pkrtz(a, b));
}

// Counted-prefetch barrier: wait for the PREVIOUS iteration's staging (its
// latency was hidden under a full iteration of compute), then raw barrier.
// sched_barrier keeps the compiler from hoisting LDS reads above it.
__device__ __forceinline__ void wait_barrier() {
  asm volatile("s_waitcnt vmcnt(0)" ::: "memory");
  __builtin_amdgcn_s_barrier();
  __builtin_amdgcn_sched_barrier(0);
}

// ---------------------------------------------------------------- converts
// One launch for x + all 4 weights: grid 8192 blocks x 1024 elems.
__global__ __launch_bounds__(256) void cvt_all(
    const float* __restrict__ x,
    const float* __restrict__ w0, const float* __restrict__ w1,
    const float* __restrict__ w2, const float* __restrict__ w3,
    u16* __restrict__ ox, u16* __restrict__ o0, u16* __restrict__ o1,
    u16* __restrict__ o2, u16* __restrict__ o3) {
  int bid = blockIdx.x;
  const float* in; u16* out; size_t off;
  if (bid < 4096) {
    in = x; out = ox; off = (size_t)bid << 10;
  } else {
    int r = bid - 4096, z = r >> 10;
    in  = (z == 0) ? w0 : (z == 1) ? w1 : (z == 2) ? w2 : w3;
    out = (z == 0) ? o0 : (z == 1) ? o1 : (z == 2) ? o2 : o3;
    off = (size_t)(r & 1023) << 10;
  }
  size_t i = off + (size_t)threadIdx.x * 4;
  float4 f = *reinterpret_cast<const float4*>(in + i);
  u64 v = (u64)pk2(f.x, f.y) | ((u64)pk2(f.z, f.w) << 32);
  *reinterpret_cast<u64*>(out + i) = v;
}

// ---------------------------------------------------------------- GEMM (B^T)
// C[m,n] = sum_k A[m,k] * Bw[n,k]; Bw:[1024,1024] bf16.
// Tile MT x NT, BK=32, 4 waves (2x2). Counted-prefetch schedule:
// {wait+barrier; stage(next); compute(cur)} -> staging latency hidden under
// a full iteration of compute.
template<int MODE, int MT, int NT>  // MODE 0: bf16 [B,H,T,D] (scaled); 1: fp32 [M,1024]
__device__ __forceinline__ void gemm_bt_body(
    const u16* __restrict__ A, const u16* __restrict__ Bw, void* __restrict__ Cout,
    int m0, int n0, float scale) {
  const int K = 1024;
  __shared__ __align__(16) u16 As[2][MT * 32];
  __shared__ __align__(16) u16 Bs[2][NT * 32];
  const int tid = threadIdx.x;
  const int lane = tid & 63, wid = tid >> 6;
  const int wr = wid >> 1, wc = wid & 1;
  const int g = lane >> 4, c = lane & 15;
  f32x4 acc[MT / 32][NT / 32] = {};

  auto stage = [&](int buf, int k0) {
#pragma unroll
    for (int i = 0; i < MT / 64; ++i) {
      int idx = tid + i * 256;
      int row = idx >> 2, slot = idx & 3;
      int ss = slot ^ (row & 3);
      GLOAD16(A + (size_t)(m0 + row) * K + k0 + ss * 8, &As[buf][idx * 8]);
    }
#pragma unroll
    for (int i = 0; i < NT / 64; ++i) {
      int idx = tid + i * 256;
      int row = idx >> 2, slot = idx & 3;
      int ss = slot ^ (row & 3);
      GLOAD16(Bw + (size_t)(n0 + row) * K + k0 + ss * 8, &Bs[buf][idx * 8]);
    }
  };

  stage(0, 0);
  int buf = 0;
#pragma unroll 1
  for (int kt = 0; kt < 32; ++kt) {
    wait_barrier();
    if (kt + 1 < 32) stage(buf ^ 1, (kt + 1) * 32);
    bf16x8 af[MT / 32], bfr[NT / 32];
#pragma unroll
    for (int mi = 0; mi < MT / 32; ++mi) {
      int row = wr * (MT / 2) + mi * 16 + c;
      int slot = g ^ (row & 3);
      af[mi] = *(const bf16x8*)&As[buf][row * 32 + slot * 8];
    }
#pragma unroll
    for (int ni = 0; ni < NT / 32; ++ni) {
      int row = wc * (NT / 2) + ni * 16 + c;
      int slot = g ^ (row & 3);
      bfr[ni] = *(const bf16x8*)&Bs[buf][row * 32 + slot * 8];
    }
    __builtin_amdgcn_s_setprio(1);
#pragma unroll
    for (int mi = 0; mi < MT / 32; ++mi)
#pragma unroll
      for (int ni = 0; ni < NT / 32; ++ni)
        acc[mi][ni] = __builtin_amdgcn_mfma_f32_16x16x32_bf16(af[mi], bfr[ni], acc[mi][ni], 0, 0, 0);
    __builtin_amdgcn_s_setprio(0);
    buf ^= 1;
  }

#pragma unroll
  for (int mi = 0; mi < MT / 32; ++mi)
#pragma unroll
    for (int ni = 0; ni < NT / 32; ++ni)
#pragma unroll
      for (int i = 0; i < 4; ++i) {
        int m = m0 + wr * (MT / 2) + mi * 16 + g * 4 + i;
        int n = n0 + wc * (NT / 2) + ni * 16 + c;
        float v = acc[mi][ni][i];
        if (MODE == 0) {
          int b = m >> 11, t = m & 2047, h = n >> 6, d = n & 63;
          ((u16*)Cout)[(((size_t)b * 16 + h) * 2048 + t) * 64 + d] = f2bf(v * scale);
        } else {
          ((float*)Cout)[(size_t)m * 1024 + n] = v;
        }
      }
}

// Q is pre-scaled by (1/sqrt(D)) * log2(e) so attn scores are in log2 domain.
#define QSCALE 0.1803368801111204f

__global__ __launch_bounds__(256, 3) void proj_qkv(
    const u16* __restrict__ xb, const u16* __restrict__ wq, const u16* __restrict__ wk,
    const u16* __restrict__ wv, u16* __restrict__ q, u16* __restrict__ k, u16* __restrict__ v) {
  int z = blockIdx.z;
  const u16* W = (z == 0) ? wq : (z == 1) ? wk : wv;
  u16* O = (z == 0) ? q : (z == 1) ? k : v;
  float scale = (z == 0) ? QSCALE : 1.0f;
  gemm_bt_body<0, 128, 128>(xb, W, O, blockIdx.y * 128, blockIdx.x * 128, scale);
}

// 64x64 tiles: grid (16, 64) = 1024 blocks -> 4 blocks/CU (TLP over density,
// per the round-7 lesson).
__global__ __launch_bounds__(256, 4) void gemm_out(
    const u16* __restrict__ y, const u16* __restrict__ wp, float* __restrict__ out) {
  gemm_bt_body<1, 64, 64>(y, wp, out, blockIdx.y * 64, blockIdx.x * 64, 1.0f);
}

// ---------------------------------------------------------------- V transpose
// v [B,H,T,64] bf16 -> vt [B,H,64,T] FP16, with per-64-tile key permutation:
// storage slot j holds real key real(j) = (2*((j>>2)&1) + (j>>5))*16
// + ((j>>3)&3)*4 + (j&3). This matches the in-register P fragment produced by
// the swapped QK^T in attn, so PV contracts correctly.
__global__ __launch_bounds__(256) void transpose_v_kernel(
    const u16* __restrict__ v, u16* __restrict__ vt) {
  __shared__ u16 tile[64][65];
  int bh = blockIdx.y, t0 = blockIdx.x * 64;
  const u16* src = v + ((size_t)bh * 2048 + t0) * 64;
  u16* dst = vt + (size_t)bh * 64 * 2048 + t0;
  int tid = threadIdx.x;
#pragma unroll
  for (int i = 0; i < 16; ++i) {
    int idx = tid + i * 256;
    tile[idx >> 6][idx & 63] = src[idx];
  }
  __syncthreads();
#pragma unroll
  for (int i = 0; i < 16; ++i) {
    int idx = tid + i * 256;
    int d = idx >> 6, j = idx & 63;
    int t = (((((j >> 2) & 1) << 1) | (j >> 5)) << 4) | (((j >> 3) & 3) << 2) | (j & 3);
    float f = __builtin_bit_cast(float, (u32)tile[t][d] << 16);
    _Float16 hh = (_Float16)f;
    dst[(size_t)d * 2048 + j] = __builtin_bit_cast(u16, hh);
  }
}

// ---------------------------------------------------------------- flash attention
// grid (32 bh, 32): 64 q-rows/block (4 waves x 16), KVBLK=64, 32KB LDS,
// 4 blocks/CU. qt remap balances per-CU work: co-resident blocks (linear ids
// differing by 256 -> same CU) have y in {o,o+8,o+16,o+24}; qt(y) =
// {o, 31-o, 8+o, 23-o} makes every CU's iteration sum exactly 66.
// SWAPPED QK^T: mfma(K,Q) -> lane (g,c) holds 16 scores for q-row (qrow0+c),
// keys ni*16+g*4+i. With the matching V storage permutation, the PV A-frag
// is packed fully IN REGISTERS (8 pkh) -> no P LDS round-trip at all.
// FIXED-BASE softmax: p = exp2(s) directly (log2-domain scores, bounded;
// fp32 exp2 headroom ~2^116). Row-sums via MFMA vs all-ones. Counted-prefetch
// barrier at loop top hides staging latency under a full iteration.
__global__ __launch_bounds__(256, 4) void attn_kernel(
    const u16* __restrict__ q, const u16* __restrict__ kg,
    const u16* __restrict__ vt, u16* __restrict__ y) {
  const int T = 2048;
  __shared__ __align__(16) u16 Ks[2][64 * 64];   // [key][d] bf16
  __shared__ __align__(16) u16 Vs[2][64 * 64];   // [d][key-slot] fp16 (perm'd)
  const int tid = threadIdx.x, lane = tid & 63, w = tid >> 6;
  const int g = lane >> 4, c = lane & 15;
  const int bh = blockIdx.x;
  const int yy = blockIdx.y, m8 = yy >> 3, o8 = yy & 7;
  const int qt = (m8 == 0) ? o8 : (m8 == 1) ? 31 - o8 : (m8 == 2) ? 8 + o8 : 23 - o8;
  const u16* Q = q + (size_t)bh * T * 64;
  const u16* K = kg + (size_t)bh * T * 64;
  const u16* V = vt + (size_t)bh * 64 * T;
  const int b = bh >> 4, h = bh & 15;
  const int qrow0 = qt * 64 + w * 16;

  f16x8 ones;
#pragma unroll
  for (int j = 0; j < 8; ++j) ones[j] = (_Float16)1.0f;

  auto stage = [&](int bb, int j0) {
#pragma unroll
    for (int i = 0; i < 2; ++i) {
      int idx = tid + i * 256;
      int row = idx >> 3, slot = idx & 7;
      int ss = slot ^ (row & 7);
      GLOAD16(K + (size_t)(j0 + row) * 64 + ss * 8, &Ks[bb][idx * 8]);
      GLOAD16(V + (size_t)row * T + j0 + ss * 8, &Vs[bb][idx * 8]);
    }
  };

  bf16x8 qf[2];
#pragma unroll
  for (int kk = 0; kk < 2; ++kk)
    qf[kk] = *(const bf16x8*)&Q[(size_t)(qrow0 + c) * 64 + kk * 32 + g * 8];

  f32x4 o[4] = {};
  f32x4 ol = {};   // row-sums (every column identical)

  const int nkt = qt + 1;
  stage(0, 0);
  int buf = 0;
#pragma unroll 1
  for (int kt = 0; kt < nkt; ++kt) {
    const int j0 = kt * 64;
    wait_barrier();
    if (kt + 1 < nkt) stage(buf ^ 1, j0 + 64);

    // S^T = K Q^T: s[ni][i] = S[q-row qrow0+c][key j0 + ni*16 + g*4 + i]
    bf16x8 kb[4][2];
#pragma unroll
    for (int ni = 0; ni < 4; ++ni)
#pragma unroll
      for (int kk = 0; kk < 2; ++kk) {
        int kr = ni * 16 + c;
        int slot = (kk * 4 + g) ^ (kr & 7);
        kb[ni][kk] = *(const bf16x8*)&Ks[buf][kr * 64 + slot * 8];
      }
    f32x4 s[4];
    __builtin_amdgcn_s_setprio(1);
#pragma unroll
    for (int ni = 0; ni < 4; ++ni) {
      f32x4 a = {0.f, 0.f, 0.f, 0.f};
      a = __builtin_amdgcn_mfma_f32_16x16x32_bf16(kb[ni][0], qf[0], a, 0, 0, 0);
      a = __builtin_amdgcn_mfma_f32_16x16x32_bf16(kb[ni][1], qf[1], a, 0, 0, 0);
      s[ni] = a;
    }
    __builtin_amdgcn_s_setprio(0);

    // p = exp2(s); causal mask -> -inf -> 0 (only diag tile masks)
    const bool dumask = (kt == qt);
#pragma unroll
    for (int ni = 0; ni < 4; ++ni)
#pragma unroll
      for (int i = 0; i < 4; ++i) {
        float val = s[ni][i];
        if (dumask) {
          int key = j0 + ni * 16 + g * 4 + i;
          if (key > qrow0 + c) val = -3.0e38f;
        }
        s[ni][i] = __builtin_amdgcn_exp2f(val);
      }

    // In-register P fragment (fp16): storage slot b*32+g*8+q*4+i holds real
    // key (2q+b)*16+g*4+i = s[2q+b][i]. Matches V's storage permutation.
    u32x4 pa0 = { pkh(s[0][0], s[0][1]), pkh(s[0][2], s[0][3]),
                  pkh(s[2][0], s[2][1]), pkh(s[2][2], s[2][3]) };
    u32x4 pa1 = { pkh(s[1][0], s[1][1]), pkh(s[1][2], s[1][3]),
                  pkh(s[3][0], s[3][1]), pkh(s[3][2], s[3][3]) };
    f16x8 pa[2];
    pa[0] = __builtin_bit_cast(f16x8, pa0);
    pa[1] = __builtin_bit_cast(f16x8, pa1);

    // O += P @ V; l += P @ 1 (fp16 inputs, fp32 accum)
    f16x8 vb[4][2];
#pragma unroll
    for (int di = 0; di < 4; ++di)
#pragma unroll
      for (int kk = 0; kk < 2; ++kk) {
        int d = di * 16 + c;
        int slot = (kk * 4 + g) ^ (d & 7);
        vb[di][kk] = *(const f16x8*)&Vs[buf][d * 64 + slot * 8];
      }
    __builtin_amdgcn_s_setprio(1);
    ol = __builtin_amdgcn_mfma_f32_16x16x32_f16(pa[0], ones, ol, 0, 0, 0);
    ol = __builtin_amdgcn_mfma_f32_16x16x32_f16(pa[1], ones, ol, 0, 0, 0);
#pragma unroll
    for (int di = 0; di < 4; ++di) {
      o[di] = __builtin_amdgcn_mfma_f32_16x16x32_f16(pa[0], vb[di][0], o[di], 0, 0, 0);
      o[di] = __builtin_amdgcn_mfma_f32_16x16x32_f16(pa[1], vb[di][1], o[di], 0, 0, 0);
    }
    __builtin_amdgcn_s_setprio(0);
    buf ^= 1;
  }

  // epilogue: y[b, t, h*64 + d] = o / l   (o rows = q-rows g*4+i, cols = d)
#pragma unroll
  for (int i = 0; i < 4; ++i) {
    float inv = 1.f / ol[i];
    int t = qrow0 + g * 4 + i;
#pragma unroll
    for (int di = 0; di < 4; ++di) {
      int col = h * 64 + di * 16 + c;
      y[((size_t)b * 2048 + t) * 1024 + col] = f2bf(o[di][i] * inv);
    }
  }
}

// ---------------------------------------------------------------- launch
extern "C" void kernel_launch(void* const* d_in, const int* in_sizes, int n_in,
                              void* d_out, int out_size, void* d_ws, size_t ws_size,
                              hipStream_t stream) {
  // setup_inputs order: x, Wk, Wq, Wv, Wp
  const float* x  = (const float*)d_in[0];
  const float* Wk = (const float*)d_in[1];
  const float* Wq = (const float*)d_in[2];
  const float* Wv = (const float*)d_in[3];
  const float* Wp = (const float*)d_in[4];
  float* out = (float*)d_out;

  char* ws = (char*)d_ws;
  const size_t SZ_X = (size_t)4096 * 1024 * 2;  // 8 MiB (x_bf16 / q / k / v each)
  const size_t SZ_W = (size_t)1024 * 1024 * 2;  // 2 MiB per weight
  u16* xb  = (u16*)(ws);                  // x bf16; reused as vt (fp16) after proj
  u16* qb  = (u16*)(ws + SZ_X);
  u16* kb  = (u16*)(ws + 2 * SZ_X);
  u16* vb  = (u16*)(ws + 3 * SZ_X);       // v [B,H,T,D]; reused as y after transpose
  u16* wqb = (u16*)(ws + 4 * SZ_X);
  u16* wkb = (u16*)(ws + 4 * SZ_X + SZ_W);
  u16* wvb = (u16*)(ws + 4 * SZ_X + 2 * SZ_W);
  u16* wpb = (u16*)(ws + 4 * SZ_X + 3 * SZ_W);
  // total workspace: 40 MiB

  cvt_all<<<8192, 256, 0, stream>>>(x, Wq, Wk, Wv, Wp, xb, wqb, wkb, wvb, wpb);

  proj_qkv<<<dim3(8, 32, 3), 256, 0, stream>>>(xb, wqb, wkb, wvb, qb, kb, vb);

  u16* vtb = xb;  // x_bf16 is dead after projections
  transpose_v_kernel<<<dim3(32, 32), 256, 0, stream>>>(vb, vtb);

  u16* yb = vb;   // v [B,H,T,D] is dead after transpose
  attn_kernel<<<dim3(32, 32), 256, 0, stream>>>(qb, kb, vtb, yb);

  gemm_out<<<dim3(16, 64), 256, 0, stream>>>(yb, wpb, out);
}